// Round 9
// baseline (192.396 us; speedup 1.0000x reference)
//
#include <hip/hip_runtime.h>
#include <hip/hip_bf16.h>

#define N_NODES 50000
#define N_EDGES 800000
#define IN_FT 256
#define OUT_FT 128

typedef __bf16 bf16;
typedef __attribute__((ext_vector_type(8))) __bf16 bf16x8;
typedef __attribute__((ext_vector_type(4))) float floatx4;

static __device__ inline unsigned short f2bf_bits(float f) {
    unsigned u = __float_as_uint(f);
    return (unsigned short)((u + 0x7FFFu + ((u >> 16) & 1u)) >> 16);  // RTNE
}

// ================= config =================
#define P 256
#define CHUNK (N_EDGES / P)              // 3125
#define NBUCK ((N_NODES + 255) / 256)    // 196
#define NSCAN (NBUCK * P)                // 50176
#define GM 128
#define GEMM_BLKS ((N_NODES + GM - 1) / GM)   // 391
#define WP 264
#define PSB 128                          // pscat blocks (each = 2 phist chunks)
#define GF_CAP 4096                      // LDS edge cap per half-bucket (max ~2350)

// ============ launch 1: phist (0..255) + zero status/ticket (256)
//              + wconv (257..288) ============
__global__ __launch_bounds__(256) void k_prep(const float* __restrict__ W,
                                              const int* __restrict__ dst,
                                              unsigned short* __restrict__ Wb,
                                              int* __restrict__ cnt,
                                              unsigned long long* __restrict__ status,
                                              int* __restrict__ ticket) {
    const int b = blockIdx.x, t = threadIdx.x;
    if (b < P) {
        __shared__ int h[NBUCK];
        if (t < NBUCK) h[t] = 0;
        __syncthreads();
        const int base = b * CHUNK;
        for (int i = t; i < CHUNK; i += 256)
            atomicAdd(&h[dst[base + i] >> 8], 1);
        __syncthreads();
        if (t < NBUCK) cnt[t * P + b] = h[t];
    } else if (b == P) {
        if (t < NBUCK) status[t] = 0ull;
        if (t == 255) *ticket = 0;
    } else {
        int i = (b - P - 1) * 256 + t;          // 8192 float4 groups
        float4 v = ((const float4*)W)[i];
        ushort4 o;
        o.x = f2bf_bits(v.x); o.y = f2bf_bits(v.y);
        o.z = f2bf_bits(v.z); o.w = f2bf_bits(v.w);
        ((ushort4*)Wb)[i] = o;
    }
}

// ============ launch 2: decoupled-lookback scan over cnt (tile == bucket) ====
__global__ __launch_bounds__(256) void k_scan(const int* __restrict__ cnt,
                                              int* __restrict__ cnt_off,
                                              int* __restrict__ partoff,
                                              unsigned long long* __restrict__ status,
                                              int* __restrict__ ticket) {
    __shared__ int lds2[256];
    __shared__ int stile;
    __shared__ unsigned run_sh;
    const int t = threadIdx.x;
    if (t == 0) stile = atomicAdd(ticket, 1);
    __syncthreads();
    const int j = stile;
    int v = cnt[j * 256 + t];
    lds2[t] = v;
    __syncthreads();
    for (int s = 1; s < 256; s <<= 1) {
        int add = (t >= s) ? lds2[t - s] : 0;
        __syncthreads();
        lds2[t] += add;
        __syncthreads();
    }
    const unsigned total = (unsigned)lds2[255];
    if (t == 0) {
        if (j == 0) {
            atomicExch(&status[0], ((unsigned long long)total << 2) | 2ull);
            run_sh = 0;
        } else {
            atomicExch(&status[j], ((unsigned long long)total << 2) | 1ull);
            unsigned running = 0;
            int k = j - 1;
            for (;;) {
                unsigned long long s = atomicAdd(&status[k], 0ull);
                unsigned st = (unsigned)(s & 3ull);
                if (st == 0u) { __builtin_amdgcn_s_sleep(1); continue; }
                running += (unsigned)(s >> 2);
                if (st == 2u) break;
                --k;
            }
            atomicExch(&status[j],
                       ((unsigned long long)(running + total) << 2) | 2ull);
            run_sh = running;
        }
    }
    __syncthreads();
    const int base = (int)run_sh;
    cnt_off[j * 256 + t] = base + lds2[t] - v;
    if (t == 0) partoff[j] = base;
    if (t == 0 && j == NBUCK - 1) partoff[NBUCK] = base + (int)total;
}

// ============ launch 3: gemm (0..390) ∥ pscat (391..518) — independent ======
__global__ __launch_bounds__(512) void k_gemm_pscat(const float* __restrict__ seq,
                                                    const unsigned short* __restrict__ Wb,
                                                    unsigned short* __restrict__ seq_fts,
                                                    const int* __restrict__ src,
                                                    const int* __restrict__ dst,
                                                    const float* __restrict__ val,
                                                    const int* __restrict__ cnt_off,
                                                    uint2* __restrict__ part_ev) {
    const int t = threadIdx.x;
    if (blockIdx.x < GEMM_BLKS) {
        // ---------------- bf16 MFMA GEMM, 128 rows/block ----------------
        __shared__ bf16 Wlds[128 * WP];
        {
            const int row = t >> 2, c0 = (t & 3) * 64;
            const unsigned short* srcp = Wb + row * IN_FT + c0;
            bf16* dstp = Wlds + row * WP + c0;
#pragma unroll
            for (int c = 0; c < 8; ++c)
                *(uint4*)(dstp + c * 8) = *(const uint4*)(srcp + c * 8);
        }
        const int lane = t & 63;
        const int wave = t >> 6;
        const int quad = lane >> 4;
        const int l16  = lane & 15;

        int arow = blockIdx.x * GM + wave * 16 + l16;
        if (arow >= N_NODES) arow = 0;            // clamped; stores guarded
        const float* ap = seq + (size_t)arow * IN_FT + quad * 8;
        bf16x8 afr[8];
#pragma unroll
        for (int s = 0; s < 8; ++s) {
            float4 v0 = *(const float4*)(ap + s * 32);
            float4 v1 = *(const float4*)(ap + s * 32 + 4);
            bf16x8 a;
            a[0] = (bf16)v0.x; a[1] = (bf16)v0.y; a[2] = (bf16)v0.z; a[3] = (bf16)v0.w;
            a[4] = (bf16)v1.x; a[5] = (bf16)v1.y; a[6] = (bf16)v1.z; a[7] = (bf16)v1.w;
            afr[s] = a;
        }
        __syncthreads();

        const int mbase = blockIdx.x * GM + wave * 16;
#pragma unroll
        for (int tt = 0; tt < 8; ++tt) {
            floatx4 acc = {0.f, 0.f, 0.f, 0.f};
            const bf16* bp = Wlds + (tt * 16 + l16) * WP + quad * 8;
#pragma unroll
            for (int s = 0; s < 8; ++s) {
                bf16x8 bfr = *(const bf16x8*)(bp + s * 32);
                acc = __builtin_amdgcn_mfma_f32_16x16x32_bf16(afr[s], bfr, acc, 0, 0, 0);
            }
#pragma unroll
            for (int r = 0; r < 4; ++r) {
                int m = mbase + quad * 4 + r;   // C/D: row = quad*4+reg, col = l16
                if (m < N_NODES)
                    seq_fts[(size_t)m * OUT_FT + tt * 16 + l16] = f2bf_bits(acc[r]);
            }
        }
    } else {
        // ------------- partition scatter: 2 phist-chunks per block ---------
        __shared__ int off2[2][NBUCK];
        const int pb = blockIdx.x - GEMM_BLKS;   // 0..127
        if (t < NBUCK)
            off2[0][t] = cnt_off[t * P + 2 * pb];
        else if (t >= 256 && t - 256 < NBUCK)
            off2[1][t - 256] = cnt_off[(t - 256) * P + 2 * pb + 1];
        __syncthreads();
        const int c  = t >> 8;                   // 0 or 1
        const int tt = t & 255;
        const int base = (2 * pb + c) * CHUNK;
        for (int i = tt; i < CHUNK; i += 256) {
            int e = base + i;
            int d = dst[e];
            int pos = atomicAdd(&off2[c][d >> 8], 1);
            unsigned x = (unsigned)(unsigned short)src[e]
                       | ((unsigned)f2bf_bits(val[e]) << 16);
            part_ev[pos] = make_uint2(x, (unsigned)d);
        }
    }
}

// ============ launch 4: fused node-grouping + gather + bias + PReLU =========
// 2 blocks per bucket (half = 128 nodes each), 512 thr. Node-grouped edge
// payloads built in LDS from part_ev (no csr_ev / row_ptr round-trip), then
// 8 waves gather: wave handles 16 nodes, lane = feature pair (bf16x2 dword).
__global__ __launch_bounds__(512) void k_gfill(const uint2* __restrict__ part_ev,
                                               const int* __restrict__ partoff,
                                               const unsigned* __restrict__ fts,
                                               const float* __restrict__ bias,
                                               const float* __restrict__ prelu_a,
                                               float* __restrict__ out) {
    __shared__ unsigned pay[GF_CAP];
    __shared__ int cnt[128], pfx[128], cur[128];
    const int fb   = blockIdx.x;
    const int b    = fb >> 1;
    const int half = fb & 1;
    const int t    = threadIdx.x;
    const int start = partoff[b];
    const int end   = partoff[b + 1];

    if (t < 128) cnt[t] = 0;
    __syncthreads();
    for (int i = start + t; i < end; i += 512) {
        unsigned rel = part_ev[i].y & 255u;
        if ((int)(rel >> 7) == half) atomicAdd(&cnt[rel & 127u], 1);
    }
    __syncthreads();
    if (t < 128) pfx[t] = cnt[t];
    __syncthreads();
#pragma unroll
    for (int s = 1; s < 128; s <<= 1) {
        int add = (t < 128 && t >= s) ? pfx[t - s] : 0;
        __syncthreads();
        if (t < 128) pfx[t] += add;
        __syncthreads();
    }
    if (t < 128) cur[t] = pfx[t] - cnt[t];   // exclusive start
    __syncthreads();
    for (int i = start + t; i < end; i += 512) {
        uint2 r = part_ev[i];
        unsigned rel = r.y & 255u;
        if ((int)(rel >> 7) == half) {
            int pos = atomicAdd(&cur[rel & 127u], 1);
            if (pos < GF_CAP) pay[pos] = r.x;
        }
    }
    __syncthreads();

    // ---- gather phase: 8 waves × 16 nodes each ----
    const int wave = t >> 6;
    const int lane = t & 63;
    const float2 bi = *(const float2*)&bias[lane * 2];
    const float a = prelu_a[0];
#pragma unroll
    for (int q = 0; q < 16; ++q) {
        const int ln = wave * 16 + q;
        const int n  = b * 256 + half * 128 + ln;
        if (n >= N_NODES) continue;
        const int s1 = pfx[ln];
        const int s0 = s1 - cnt[ln];
        float acc0 = 0.f, acc1 = 0.f;
        int j = s0;
        for (; j + 3 < s1; j += 4) {
            unsigned w0 = pay[j],     w1 = pay[j + 1];
            unsigned w2 = pay[j + 2], w3 = pay[j + 3];
            unsigned p0 = fts[(w0 & 0xFFFFu) * 64u + lane];
            unsigned p1 = fts[(w1 & 0xFFFFu) * 64u + lane];
            unsigned p2 = fts[(w2 & 0xFFFFu) * 64u + lane];
            unsigned p3 = fts[(w3 & 0xFFFFu) * 64u + lane];
            float v0 = __uint_as_float(w0 & 0xFFFF0000u);
            float v1 = __uint_as_float(w1 & 0xFFFF0000u);
            float v2 = __uint_as_float(w2 & 0xFFFF0000u);
            float v3 = __uint_as_float(w3 & 0xFFFF0000u);
            acc0 += v0 * __uint_as_float(p0 << 16);
            acc1 += v0 * __uint_as_float(p0 & 0xFFFF0000u);
            acc0 += v1 * __uint_as_float(p1 << 16);
            acc1 += v1 * __uint_as_float(p1 & 0xFFFF0000u);
            acc0 += v2 * __uint_as_float(p2 << 16);
            acc1 += v2 * __uint_as_float(p2 & 0xFFFF0000u);
            acc0 += v3 * __uint_as_float(p3 << 16);
            acc1 += v3 * __uint_as_float(p3 & 0xFFFF0000u);
        }
        for (; j < s1; ++j) {
            unsigned w0 = pay[j];
            unsigned p0 = fts[(w0 & 0xFFFFu) * 64u + lane];
            float v0 = __uint_as_float(w0 & 0xFFFF0000u);
            acc0 += v0 * __uint_as_float(p0 << 16);
            acc1 += v0 * __uint_as_float(p0 & 0xFFFF0000u);
        }
        float x0 = acc0 + bi.x;
        float x1 = acc1 + bi.y;
        x0 = (x0 >= 0.f) ? x0 : a * x0;
        x1 = (x1 >= 0.f) ? x1 : a * x1;
        *(float2*)&out[(size_t)n * OUT_FT + lane * 2] = make_float2(x0, x1);
    }
}

extern "C" void kernel_launch(void* const* d_in, const int* in_sizes, int n_in,
                              void* d_out, int out_size, void* d_ws, size_t ws_size,
                              hipStream_t stream) {
    const float* seq      = (const float*)d_in[0];
    const int*   edge_src = (const int*)d_in[1];
    const int*   edge_dst = (const int*)d_in[2];
    const float* edge_val = (const float*)d_in[3];
    const float* W        = (const float*)d_in[4];
    const float* bias     = (const float*)d_in[5];
    const float* prelu_a  = (const float*)d_in[6];
    float* out = (float*)d_out;

    char* ws = (char*)d_ws;
    size_t off = 0;
    auto alloc = [&](size_t bytes) {
        void* p = ws + off;
        off = (off + bytes + 255) & ~(size_t)255;
        return p;
    };
    unsigned short* seq_fts = (unsigned short*)alloc((size_t)N_NODES * OUT_FT * sizeof(unsigned short));
    unsigned short* Wb      = (unsigned short*)alloc((size_t)OUT_FT * IN_FT * sizeof(unsigned short));
    int*   cnt     = (int*)alloc((size_t)NSCAN * sizeof(int));
    int*   cnt_off = (int*)alloc((size_t)NSCAN * sizeof(int));
    int*   partoff = (int*)alloc((size_t)(NBUCK + 1) * sizeof(int));
    unsigned long long* status = (unsigned long long*)alloc((size_t)NBUCK * sizeof(unsigned long long));
    int*   ticket  = (int*)alloc(256);
    uint2* part_ev = (uint2*)alloc((size_t)N_EDGES * sizeof(uint2));
    (void)ws_size; (void)in_sizes; (void)n_in; (void)out_size;

    k_prep<<<P + 1 + 32, 256, 0, stream>>>(W, edge_dst, Wb, cnt, status, ticket);
    k_scan<<<NBUCK, 256, 0, stream>>>(cnt, cnt_off, partoff, status, ticket);
    k_gemm_pscat<<<GEMM_BLKS + PSB, 512, 0, stream>>>(seq, Wb, seq_fts,
                                                      edge_src, edge_dst, edge_val,
                                                      cnt_off, part_ev);
    k_gfill<<<NBUCK * 2, 512, 0, stream>>>(part_ev, partoff, (const unsigned*)seq_fts,
                                           bias, prelu_a, out);
}

// Round 10
// 186.625 us; speedup vs baseline: 1.0309x; 1.0309x over previous
//
#include <hip/hip_runtime.h>
#include <hip/hip_bf16.h>

#define N_NODES 50000
#define N_EDGES 800000
#define IN_FT 256
#define OUT_FT 128

typedef __bf16 bf16;
typedef __attribute__((ext_vector_type(8))) __bf16 bf16x8;
typedef __attribute__((ext_vector_type(4))) float floatx4;

static __device__ inline unsigned short f2bf_bits(float f) {
    unsigned u = __float_as_uint(f);
    return (unsigned short)((u + 0x7FFFu + ((u >> 16) & 1u)) >> 16);  // RTNE
}

// ================= config =================
#define P 256
#define CHUNK (N_EDGES / P)              // 3125
#define NBUCK ((N_NODES + 255) / 256)    // 196
#define NSCAN (NBUCK * P)                // 50176
#define GM 128
#define GEMM_BLKS ((N_NODES + GM - 1) / GM)   // 391
#define WP 264
#define PSB 128                          // pscat blocks (each = 2 phist chunks)

// ============ launch 1: phist (0..255) + zero status/ticket (256)
//              + wconv (257..288) ============
__global__ __launch_bounds__(256) void k_prep(const float* __restrict__ W,
                                              const int* __restrict__ dst,
                                              unsigned short* __restrict__ Wb,
                                              int* __restrict__ cnt,
                                              unsigned long long* __restrict__ status,
                                              int* __restrict__ ticket) {
    const int b = blockIdx.x, t = threadIdx.x;
    if (b < P) {
        __shared__ int h[NBUCK];
        if (t < NBUCK) h[t] = 0;
        __syncthreads();
        const int base = b * CHUNK;
        for (int i = t; i < CHUNK; i += 256)
            atomicAdd(&h[dst[base + i] >> 8], 1);
        __syncthreads();
        if (t < NBUCK) cnt[t * P + b] = h[t];
    } else if (b == P) {
        if (t < NBUCK) status[t] = 0ull;
        if (t == 255) *ticket = 0;
    } else {
        int i = (b - P - 1) * 256 + t;          // 8192 float4 groups
        float4 v = ((const float4*)W)[i];
        ushort4 o;
        o.x = f2bf_bits(v.x); o.y = f2bf_bits(v.y);
        o.z = f2bf_bits(v.z); o.w = f2bf_bits(v.w);
        ((ushort4*)Wb)[i] = o;
    }
}

// ============ launch 2: decoupled-lookback scan over cnt (tile == bucket) ====
__global__ __launch_bounds__(256) void k_scan(const int* __restrict__ cnt,
                                              int* __restrict__ cnt_off,
                                              int* __restrict__ partoff,
                                              unsigned long long* __restrict__ status,
                                              int* __restrict__ ticket) {
    __shared__ int lds2[256];
    __shared__ int stile;
    __shared__ unsigned run_sh;
    const int t = threadIdx.x;
    if (t == 0) stile = atomicAdd(ticket, 1);
    __syncthreads();
    const int j = stile;
    int v = cnt[j * 256 + t];
    lds2[t] = v;
    __syncthreads();
    for (int s = 1; s < 256; s <<= 1) {
        int add = (t >= s) ? lds2[t - s] : 0;
        __syncthreads();
        lds2[t] += add;
        __syncthreads();
    }
    const unsigned total = (unsigned)lds2[255];
    if (t == 0) {
        if (j == 0) {
            atomicExch(&status[0], ((unsigned long long)total << 2) | 2ull);
            run_sh = 0;
        } else {
            atomicExch(&status[j], ((unsigned long long)total << 2) | 1ull);
            unsigned running = 0;
            int k = j - 1;
            for (;;) {
                unsigned long long s = atomicAdd(&status[k], 0ull);
                unsigned st = (unsigned)(s & 3ull);
                if (st == 0u) { __builtin_amdgcn_s_sleep(1); continue; }
                running += (unsigned)(s >> 2);
                if (st == 2u) break;
                --k;
            }
            atomicExch(&status[j],
                       ((unsigned long long)(running + total) << 2) | 2ull);
            run_sh = running;
        }
    }
    __syncthreads();
    const int base = (int)run_sh;
    cnt_off[j * 256 + t] = base + lds2[t] - v;
    if (t == 0) partoff[j] = base;
    if (t == 0 && j == NBUCK - 1) partoff[NBUCK] = base + (int)total;
}

// ============ launch 3: gemm (0..390) ∥ pscat (391..518) — independent ======
__global__ __launch_bounds__(512) void k_gemm_pscat(const float* __restrict__ seq,
                                                    const unsigned short* __restrict__ Wb,
                                                    unsigned short* __restrict__ seq_fts,
                                                    const int* __restrict__ src,
                                                    const int* __restrict__ dst,
                                                    const float* __restrict__ val,
                                                    const int* __restrict__ cnt_off,
                                                    uint2* __restrict__ part_ev) {
    const int t = threadIdx.x;
    if (blockIdx.x < GEMM_BLKS) {
        // ---------------- bf16 MFMA GEMM, 128 rows/block ----------------
        __shared__ bf16 Wlds[128 * WP];
        {
            const int row = t >> 2, c0 = (t & 3) * 64;
            const unsigned short* srcp = Wb + row * IN_FT + c0;
            bf16* dstp = Wlds + row * WP + c0;
#pragma unroll
            for (int c = 0; c < 8; ++c)
                *(uint4*)(dstp + c * 8) = *(const uint4*)(srcp + c * 8);
        }
        const int lane = t & 63;
        const int wave = t >> 6;
        const int quad = lane >> 4;
        const int l16  = lane & 15;

        int arow = blockIdx.x * GM + wave * 16 + l16;
        if (arow >= N_NODES) arow = 0;            // clamped; stores guarded
        const float* ap = seq + (size_t)arow * IN_FT + quad * 8;
        bf16x8 afr[8];
#pragma unroll
        for (int s = 0; s < 8; ++s) {
            float4 v0 = *(const float4*)(ap + s * 32);
            float4 v1 = *(const float4*)(ap + s * 32 + 4);
            bf16x8 a;
            a[0] = (bf16)v0.x; a[1] = (bf16)v0.y; a[2] = (bf16)v0.z; a[3] = (bf16)v0.w;
            a[4] = (bf16)v1.x; a[5] = (bf16)v1.y; a[6] = (bf16)v1.z; a[7] = (bf16)v1.w;
            afr[s] = a;
        }
        __syncthreads();

        const int mbase = blockIdx.x * GM + wave * 16;
#pragma unroll
        for (int tt = 0; tt < 8; ++tt) {
            floatx4 acc = {0.f, 0.f, 0.f, 0.f};
            const bf16* bp = Wlds + (tt * 16 + l16) * WP + quad * 8;
#pragma unroll
            for (int s = 0; s < 8; ++s) {
                bf16x8 bfr = *(const bf16x8*)(bp + s * 32);
                acc = __builtin_amdgcn_mfma_f32_16x16x32_bf16(afr[s], bfr, acc, 0, 0, 0);
            }
#pragma unroll
            for (int r = 0; r < 4; ++r) {
                int m = mbase + quad * 4 + r;   // C/D: row = quad*4+reg, col = l16
                if (m < N_NODES)
                    seq_fts[(size_t)m * OUT_FT + tt * 16 + l16] = f2bf_bits(acc[r]);
            }
        }
    } else {
        // ------------- partition scatter: 2 phist-chunks per block ---------
        __shared__ int off2[2][NBUCK];
        const int pb = blockIdx.x - GEMM_BLKS;   // 0..127
        if (t < NBUCK)
            off2[0][t] = cnt_off[t * P + 2 * pb];
        else if (t >= 256 && t - 256 < NBUCK)
            off2[1][t - 256] = cnt_off[(t - 256) * P + 2 * pb + 1];
        __syncthreads();
        const int c  = t >> 8;                   // 0 or 1
        const int tt = t & 255;
        const int base = (2 * pb + c) * CHUNK;
        for (int i = tt; i < CHUNK; i += 256) {
            int e = base + i;
            int d = dst[e];
            int pos = atomicAdd(&off2[c][d >> 8], 1);
            unsigned x = (unsigned)(unsigned short)src[e]
                       | ((unsigned)f2bf_bits(val[e]) << 16);
            part_ev[pos] = make_uint2(x, (unsigned)d);
        }
    }
}

// ============ launch 4: per-bucket node grouping -> row_ptr + csr_ev ========
__global__ __launch_bounds__(256) void k_fill2(const uint2* __restrict__ part_ev,
                                               const int* __restrict__ partoff,
                                               int* __restrict__ row_ptr,
                                               unsigned* __restrict__ csr_ev) {
    __shared__ int cnt[256];
    __shared__ int lds[256];
    __shared__ int cur[256];
    const int b = blockIdx.x, t = threadIdx.x;
    const int start = partoff[b];
    const int end   = partoff[b + 1];
    cnt[t] = 0;
    __syncthreads();
    for (int i = start + t; i < end; i += 256)
        atomicAdd(&cnt[part_ev[i].y & 255u], 1);
    __syncthreads();
    int v = cnt[t];
    lds[t] = v;
    __syncthreads();
#pragma unroll
    for (int s = 1; s < 256; s <<= 1) {
        int t2 = (t >= s) ? lds[t - s] : 0;
        __syncthreads();
        lds[t] += t2;
        __syncthreads();
    }
    int base = start + lds[t] - v;   // node-exclusive offset
    int n = b * 256 + t;
    if (n <= N_NODES) row_ptr[n] = base;
    cur[t] = base;
    __syncthreads();
    for (int i = start + t; i < end; i += 256) {
        uint2 r = part_ev[i];
        int pos = atomicAdd(&cur[r.y & 255u], 1);
        csr_ev[pos] = r.x;
    }
}

// ============ launch 5: gather + bias + PReLU ============
// one wave per node (50K waves — max TLP for the latency-bound gather);
// lane = feature pair (bf16x2 dword): 256 B/row per edge, fully coalesced.
#define GW 4
__global__ __launch_bounds__(64 * GW) void k_gather(const unsigned* __restrict__ fts,
                                                    const int* __restrict__ row_ptr,
                                                    const unsigned* __restrict__ csr_ev,
                                                    const float* __restrict__ bias,
                                                    const float* __restrict__ prelu_a,
                                                    float* __restrict__ out) {
    const int wave = threadIdx.x >> 6;
    const int lane = threadIdx.x & 63;
    const int n = blockIdx.x * GW + wave;
    if (n >= N_NODES) return;
    const int s0 = row_ptr[n];
    const int s1 = row_ptr[n + 1];
    float acc0 = 0.f, acc1 = 0.f;
    int j = s0;
    for (; j + 3 < s1; j += 4) {
        unsigned w0 = csr_ev[j],     w1 = csr_ev[j + 1];
        unsigned w2 = csr_ev[j + 2], w3 = csr_ev[j + 3];
        unsigned p0 = fts[(w0 & 0xFFFFu) * 64u + lane];
        unsigned p1 = fts[(w1 & 0xFFFFu) * 64u + lane];
        unsigned p2 = fts[(w2 & 0xFFFFu) * 64u + lane];
        unsigned p3 = fts[(w3 & 0xFFFFu) * 64u + lane];
        float v0 = __uint_as_float(w0 & 0xFFFF0000u);
        float v1 = __uint_as_float(w1 & 0xFFFF0000u);
        float v2 = __uint_as_float(w2 & 0xFFFF0000u);
        float v3 = __uint_as_float(w3 & 0xFFFF0000u);
        acc0 += v0 * __uint_as_float(p0 << 16);
        acc1 += v0 * __uint_as_float(p0 & 0xFFFF0000u);
        acc0 += v1 * __uint_as_float(p1 << 16);
        acc1 += v1 * __uint_as_float(p1 & 0xFFFF0000u);
        acc0 += v2 * __uint_as_float(p2 << 16);
        acc1 += v2 * __uint_as_float(p2 & 0xFFFF0000u);
        acc0 += v3 * __uint_as_float(p3 << 16);
        acc1 += v3 * __uint_as_float(p3 & 0xFFFF0000u);
    }
    for (; j < s1; ++j) {
        unsigned w0 = csr_ev[j];
        unsigned p0 = fts[(w0 & 0xFFFFu) * 64u + lane];
        float v0 = __uint_as_float(w0 & 0xFFFF0000u);
        acc0 += v0 * __uint_as_float(p0 << 16);
        acc1 += v0 * __uint_as_float(p0 & 0xFFFF0000u);
    }
    float2 b = *(const float2*)&bias[lane * 2];
    float a = prelu_a[0];
    float x0 = acc0 + b.x;
    float x1 = acc1 + b.y;
    x0 = (x0 >= 0.f) ? x0 : a * x0;
    x1 = (x1 >= 0.f) ? x1 : a * x1;
    *(float2*)&out[(size_t)n * OUT_FT + lane * 2] = make_float2(x0, x1);
}

extern "C" void kernel_launch(void* const* d_in, const int* in_sizes, int n_in,
                              void* d_out, int out_size, void* d_ws, size_t ws_size,
                              hipStream_t stream) {
    const float* seq      = (const float*)d_in[0];
    const int*   edge_src = (const int*)d_in[1];
    const int*   edge_dst = (const int*)d_in[2];
    const float* edge_val = (const float*)d_in[3];
    const float* W        = (const float*)d_in[4];
    const float* bias     = (const float*)d_in[5];
    const float* prelu_a  = (const float*)d_in[6];
    float* out = (float*)d_out;

    char* ws = (char*)d_ws;
    size_t off = 0;
    auto alloc = [&](size_t bytes) {
        void* p = ws + off;
        off = (off + bytes + 255) & ~(size_t)255;
        return p;
    };
    unsigned short* seq_fts = (unsigned short*)alloc((size_t)N_NODES * OUT_FT * sizeof(unsigned short));
    unsigned short* Wb      = (unsigned short*)alloc((size_t)OUT_FT * IN_FT * sizeof(unsigned short));
    int*   row_ptr = (int*)alloc((size_t)(N_NODES + 1) * sizeof(int));
    int*   cnt     = (int*)alloc((size_t)NSCAN * sizeof(int));
    int*   cnt_off = (int*)alloc((size_t)NSCAN * sizeof(int));
    int*   partoff = (int*)alloc((size_t)(NBUCK + 1) * sizeof(int));
    unsigned long long* status = (unsigned long long*)alloc((size_t)NBUCK * sizeof(unsigned long long));
    int*   ticket  = (int*)alloc(256);
    uint2* part_ev = (uint2*)alloc((size_t)N_EDGES * sizeof(uint2));
    unsigned* csr_ev = (unsigned*)alloc((size_t)N_EDGES * sizeof(unsigned));
    (void)ws_size; (void)in_sizes; (void)n_in; (void)out_size;

    k_prep<<<P + 1 + 32, 256, 0, stream>>>(W, edge_dst, Wb, cnt, status, ticket);
    k_scan<<<NBUCK, 256, 0, stream>>>(cnt, cnt_off, partoff, status, ticket);
    k_gemm_pscat<<<GEMM_BLKS + PSB, 512, 0, stream>>>(seq, Wb, seq_fts,
                                                      edge_src, edge_dst, edge_val,
                                                      cnt_off, part_ev);
    k_fill2<<<NBUCK, 256, 0, stream>>>(part_ev, partoff, row_ptr, csr_ev);
    k_gather<<<(N_NODES + GW - 1) / GW, 64 * GW, 0, stream>>>((const unsigned*)seq_fts,
                                                              row_ptr, csr_ev,
                                                              bias, prelu_a, out);
}

// Round 11
// 180.678 us; speedup vs baseline: 1.0649x; 1.0329x over previous
//
#include <hip/hip_runtime.h>
#include <hip/hip_bf16.h>

#define N_NODES 50000
#define N_EDGES 800000
#define IN_FT 256
#define OUT_FT 128

typedef __bf16 bf16;
typedef __attribute__((ext_vector_type(8))) __bf16 bf16x8;
typedef __attribute__((ext_vector_type(4))) float floatx4;

static __device__ inline unsigned short f2bf_bits(float f) {
    unsigned u = __float_as_uint(f);
    return (unsigned short)((u + 0x7FFFu + ((u >> 16) & 1u)) >> 16);  // RTNE
}

// ================= config =================
#define P 256
#define CHUNK (N_EDGES / P)              // 3125
#define NBUCK ((N_NODES + 255) / 256)    // 196
#define NSCAN (NBUCK * P)                // 50176
#define GM 128
#define GEMM_BLKS ((N_NODES + GM - 1) / GM)   // 391
#define WP 264

// ============ launch 1: phist (0..255) + zero status/ticket (256)
//              + wconv (257..288), all independent ============
__global__ __launch_bounds__(256) void k_prep(const float* __restrict__ W,
                                              const int* __restrict__ dst,
                                              unsigned short* __restrict__ Wb,
                                              int* __restrict__ cnt,
                                              unsigned long long* __restrict__ status,
                                              int* __restrict__ ticket) {
    const int b = blockIdx.x, t = threadIdx.x;
    if (b < P) {
        __shared__ int h[NBUCK];
        if (t < NBUCK) h[t] = 0;
        __syncthreads();
        const int base = b * CHUNK;
        for (int i = t; i < CHUNK; i += 256)
            atomicAdd(&h[dst[base + i] >> 8], 1);
        __syncthreads();
        if (t < NBUCK) cnt[t * P + b] = h[t];
    } else if (b == P) {
        if (t < NBUCK) status[t] = 0ull;
        if (t == 255) *ticket = 0;
    } else {
        int i = (b - P - 1) * 256 + t;          // 8192 float4 groups
        float4 v = ((const float4*)W)[i];
        ushort4 o;
        o.x = f2bf_bits(v.x); o.y = f2bf_bits(v.y);
        o.z = f2bf_bits(v.z); o.w = f2bf_bits(v.w);
        ((ushort4*)Wb)[i] = o;
    }
}

// ============ launch 2: gemm (blocks 0..390) ∪ lookback scan (391..586) ====
// gemm needs Wb; scan needs cnt — independent, overlap in one dispatch.
// (Pairing gemm with the tiny scan is fine; pairing with pscat regressed —
// LDS is per-kernel, and pscat needs its TLP: R10 post-mortem.)
__global__ __launch_bounds__(512) void k_gemm_scan(const float* __restrict__ seq,
                                                   const unsigned short* __restrict__ Wb,
                                                   unsigned short* __restrict__ seq_fts,
                                                   const int* __restrict__ cnt,
                                                   int* __restrict__ cnt_off,
                                                   int* __restrict__ partoff,
                                                   unsigned long long* __restrict__ status,
                                                   int* __restrict__ ticket) {
    const int t = threadIdx.x;
    if (blockIdx.x < GEMM_BLKS) {
        // ---------------- bf16 MFMA GEMM, 128 rows/block ----------------
        __shared__ bf16 Wlds[128 * WP];
        {
            const int row = t >> 2, c0 = (t & 3) * 64;
            const unsigned short* src = Wb + row * IN_FT + c0;
            bf16* dstp = Wlds + row * WP + c0;
#pragma unroll
            for (int c = 0; c < 8; ++c)
                *(uint4*)(dstp + c * 8) = *(const uint4*)(src + c * 8);
        }
        const int lane = t & 63;
        const int wave = t >> 6;
        const int quad = lane >> 4;
        const int l16  = lane & 15;

        int arow = blockIdx.x * GM + wave * 16 + l16;
        if (arow >= N_NODES) arow = 0;            // clamped; stores guarded
        const float* ap = seq + (size_t)arow * IN_FT + quad * 8;
        bf16x8 afr[8];
#pragma unroll
        for (int s = 0; s < 8; ++s) {
            float4 v0 = *(const float4*)(ap + s * 32);
            float4 v1 = *(const float4*)(ap + s * 32 + 4);
            bf16x8 a;
            a[0] = (bf16)v0.x; a[1] = (bf16)v0.y; a[2] = (bf16)v0.z; a[3] = (bf16)v0.w;
            a[4] = (bf16)v1.x; a[5] = (bf16)v1.y; a[6] = (bf16)v1.z; a[7] = (bf16)v1.w;
            afr[s] = a;
        }
        __syncthreads();

        const int mbase = blockIdx.x * GM + wave * 16;
#pragma unroll
        for (int tt = 0; tt < 8; ++tt) {
            floatx4 acc = {0.f, 0.f, 0.f, 0.f};
            const bf16* bp = Wlds + (tt * 16 + l16) * WP + quad * 8;
#pragma unroll
            for (int s = 0; s < 8; ++s) {
                bf16x8 bfr = *(const bf16x8*)(bp + s * 32);
                acc = __builtin_amdgcn_mfma_f32_16x16x32_bf16(afr[s], bfr, acc, 0, 0, 0);
            }
#pragma unroll
            for (int r = 0; r < 4; ++r) {
                int m = mbase + quad * 4 + r;   // C/D: row = quad*4+reg, col = l16
                if (m < N_NODES)
                    seq_fts[(size_t)m * OUT_FT + tt * 16 + l16] = f2bf_bits(acc[r]);
            }
        }
    } else {
        // ------------- decoupled-lookback scan, tile == bucket -------------
        __shared__ int lds2[256];
        __shared__ int stile;
        __shared__ unsigned run_sh;
        if (t == 0) stile = atomicAdd(ticket, 1);
        __syncthreads();
        const int j = stile;
        int v = (t < 256) ? cnt[j * 256 + t] : 0;
        if (t < 256) lds2[t] = v;
        __syncthreads();
        for (int s = 1; s < 256; s <<= 1) {
            int add = (t < 256 && t >= s) ? lds2[t - s] : 0;
            __syncthreads();
            if (t < 256) lds2[t] += add;
            __syncthreads();
        }
        const unsigned total = (unsigned)lds2[255];
        if (t == 0) {
            if (j == 0) {
                atomicExch(&status[0], ((unsigned long long)total << 2) | 2ull);
                run_sh = 0;
            } else {
                atomicExch(&status[j], ((unsigned long long)total << 2) | 1ull);
                unsigned running = 0;
                int k = j - 1;
                for (;;) {
                    unsigned long long s = atomicAdd(&status[k], 0ull);
                    unsigned st = (unsigned)(s & 3ull);
                    if (st == 0u) { __builtin_amdgcn_s_sleep(1); continue; }
                    running += (unsigned)(s >> 2);
                    if (st == 2u) break;
                    --k;
                }
                atomicExch(&status[j],
                           ((unsigned long long)(running + total) << 2) | 2ull);
                run_sh = running;
            }
        }
        __syncthreads();
        const int base = (int)run_sh;
        if (t < 256) cnt_off[j * 256 + t] = base + lds2[t] - v;
        if (t == 0) partoff[j] = base;
        if (t == 0 && j == NBUCK - 1) partoff[NBUCK] = base + (int)total;
    }
}

// ============ launch 3: partition scatter (standalone — needs its TLP) ======
// record: x = final csr payload (src u16 | bf16(val) << 16), y = dst.
__global__ __launch_bounds__(256) void k_pscat(const int* __restrict__ src,
                                               const int* __restrict__ dst,
                                               const float* __restrict__ val,
                                               const int* __restrict__ cnt_off,
                                               uint2* __restrict__ part_ev) {
    __shared__ int off[NBUCK];
    const int t = threadIdx.x;
    if (t < NBUCK) off[t] = cnt_off[t * P + blockIdx.x];
    __syncthreads();
    const int base = blockIdx.x * CHUNK;
    for (int i = t; i < CHUNK; i += 256) {
        int e = base + i;
        int d = dst[e];
        int pos = atomicAdd(&off[d >> 8], 1);
        unsigned x = (unsigned)(unsigned short)src[e]
                   | ((unsigned)f2bf_bits(val[e]) << 16);
        part_ev[pos] = make_uint2(x, (unsigned)d);
    }
}

// ============ launch 4: per-bucket node grouping -> row_ptr + csr_ev ========
__global__ __launch_bounds__(256) void k_fill2(const uint2* __restrict__ part_ev,
                                               const int* __restrict__ partoff,
                                               int* __restrict__ row_ptr,
                                               unsigned* __restrict__ csr_ev) {
    __shared__ int cnt[256];
    __shared__ int lds[256];
    __shared__ int cur[256];
    const int b = blockIdx.x, t = threadIdx.x;
    const int start = partoff[b];
    const int end   = partoff[b + 1];
    cnt[t] = 0;
    __syncthreads();
    for (int i = start + t; i < end; i += 256)
        atomicAdd(&cnt[part_ev[i].y & 255u], 1);
    __syncthreads();
    int v = cnt[t];
    lds[t] = v;
    __syncthreads();
#pragma unroll
    for (int s = 1; s < 256; s <<= 1) {
        int t2 = (t >= s) ? lds[t - s] : 0;
        __syncthreads();
        lds[t] += t2;
        __syncthreads();
    }
    int base = start + lds[t] - v;   // node-exclusive offset
    int n = b * 256 + t;
    if (n <= N_NODES) row_ptr[n] = base;
    cur[t] = base;
    __syncthreads();
    for (int i = start + t; i < end; i += 256) {
        uint2 r = part_ev[i];
        int pos = atomicAdd(&cur[r.y & 255u], 1);
        csr_ev[pos] = r.x;
    }
}

// ============ launch 5: gather + bias + PReLU ============
// one wave per node (50K waves — max TLP for the latency-bound gather);
// lane = feature pair (bf16x2 dword): 256 B/row per edge, fully coalesced.
#define GW 4
__global__ __launch_bounds__(64 * GW) void k_gather(const unsigned* __restrict__ fts,
                                                    const int* __restrict__ row_ptr,
                                                    const unsigned* __restrict__ csr_ev,
                                                    const float* __restrict__ bias,
                                                    const float* __restrict__ prelu_a,
                                                    float* __restrict__ out) {
    const int wave = threadIdx.x >> 6;
    const int lane = threadIdx.x & 63;
    const int n = blockIdx.x * GW + wave;
    if (n >= N_NODES) return;
    const int s0 = row_ptr[n];
    const int s1 = row_ptr[n + 1];
    float acc0 = 0.f, acc1 = 0.f;
    int j = s0;
    for (; j + 3 < s1; j += 4) {
        unsigned w0 = csr_ev[j],     w1 = csr_ev[j + 1];
        unsigned w2 = csr_ev[j + 2], w3 = csr_ev[j + 3];
        unsigned p0 = fts[(w0 & 0xFFFFu) * 64u + lane];
        unsigned p1 = fts[(w1 & 0xFFFFu) * 64u + lane];
        unsigned p2 = fts[(w2 & 0xFFFFu) * 64u + lane];
        unsigned p3 = fts[(w3 & 0xFFFFu) * 64u + lane];
        float v0 = __uint_as_float(w0 & 0xFFFF0000u);
        float v1 = __uint_as_float(w1 & 0xFFFF0000u);
        float v2 = __uint_as_float(w2 & 0xFFFF0000u);
        float v3 = __uint_as_float(w3 & 0xFFFF0000u);
        acc0 += v0 * __uint_as_float(p0 << 16);
        acc1 += v0 * __uint_as_float(p0 & 0xFFFF0000u);
        acc0 += v1 * __uint_as_float(p1 << 16);
        acc1 += v1 * __uint_as_float(p1 & 0xFFFF0000u);
        acc0 += v2 * __uint_as_float(p2 << 16);
        acc1 += v2 * __uint_as_float(p2 & 0xFFFF0000u);
        acc0 += v3 * __uint_as_float(p3 << 16);
        acc1 += v3 * __uint_as_float(p3 & 0xFFFF0000u);
    }
    for (; j < s1; ++j) {
        unsigned w0 = csr_ev[j];
        unsigned p0 = fts[(w0 & 0xFFFFu) * 64u + lane];
        float v0 = __uint_as_float(w0 & 0xFFFF0000u);
        acc0 += v0 * __uint_as_float(p0 << 16);
        acc1 += v0 * __uint_as_float(p0 & 0xFFFF0000u);
    }
    float2 b = *(const float2*)&bias[lane * 2];
    float a = prelu_a[0];
    float x0 = acc0 + b.x;
    float x1 = acc1 + b.y;
    x0 = (x0 >= 0.f) ? x0 : a * x0;
    x1 = (x1 >= 0.f) ? x1 : a * x1;
    *(float2*)&out[(size_t)n * OUT_FT + lane * 2] = make_float2(x0, x1);
}

extern "C" void kernel_launch(void* const* d_in, const int* in_sizes, int n_in,
                              void* d_out, int out_size, void* d_ws, size_t ws_size,
                              hipStream_t stream) {
    const float* seq      = (const float*)d_in[0];
    const int*   edge_src = (const int*)d_in[1];
    const int*   edge_dst = (const int*)d_in[2];
    const float* edge_val = (const float*)d_in[3];
    const float* W        = (const float*)d_in[4];
    const float* bias     = (const float*)d_in[5];
    const float* prelu_a  = (const float*)d_in[6];
    float* out = (float*)d_out;

    char* ws = (char*)d_ws;
    size_t off = 0;
    auto alloc = [&](size_t bytes) {
        void* p = ws + off;
        off = (off + bytes + 255) & ~(size_t)255;
        return p;
    };
    unsigned short* seq_fts = (unsigned short*)alloc((size_t)N_NODES * OUT_FT * sizeof(unsigned short));
    unsigned short* Wb      = (unsigned short*)alloc((size_t)OUT_FT * IN_FT * sizeof(unsigned short));
    int*   row_ptr = (int*)alloc((size_t)(N_NODES + 1) * sizeof(int));
    int*   cnt     = (int*)alloc((size_t)NSCAN * sizeof(int));
    int*   cnt_off = (int*)alloc((size_t)NSCAN * sizeof(int));
    int*   partoff = (int*)alloc((size_t)(NBUCK + 1) * sizeof(int));
    unsigned long long* status = (unsigned long long*)alloc((size_t)NBUCK * sizeof(unsigned long long));
    int*   ticket  = (int*)alloc(256);
    uint2* part_ev = (uint2*)alloc((size_t)N_EDGES * sizeof(uint2));
    unsigned* csr_ev = (unsigned*)alloc((size_t)N_EDGES * sizeof(unsigned));
    (void)ws_size; (void)in_sizes; (void)n_in; (void)out_size;

    k_prep<<<P + 1 + 32, 256, 0, stream>>>(W, edge_dst, Wb, cnt, status, ticket);
    k_gemm_scan<<<GEMM_BLKS + NBUCK, 512, 0, stream>>>(seq, Wb, seq_fts, cnt,
                                                       cnt_off, partoff, status, ticket);
    k_pscat<<<P, 256, 0, stream>>>(edge_src, edge_dst, edge_val, cnt_off, part_ev);
    k_fill2<<<NBUCK, 256, 0, stream>>>(part_ev, partoff, row_ptr, csr_ev);
    k_gather<<<(N_NODES + GW - 1) / GW, 64 * GW, 0, stream>>>((const unsigned*)seq_fts,
                                                              row_ptr, csr_ev,
                                                              bias, prelu_a, out);
}